// Round 10
// baseline (1469.547 us; speedup 1.0000x reference)
//
#include <hip/hip_runtime.h>
#include <hip/hip_bf16.h>

// OutlierAwareLinear: y = x @ W^T + b, then per-token outlier-aware fake-quant.
// M=16384 (B*S), K=2048 (D_in), N=2048 (D_out), all fp32 in/out.
//
// Pipeline:
//   1) k_convert: x,W f32 -> bf16 into d_ws
//   2) k_gemm32: 256x256x32 bf16 MFMA GEMM, 64 KiB LDS -> 2 blocks/CU
//      co-resident (r10: cross-BLOCK overlap replaces intra-block scheduling;
//      m114 mechanism). 1 barrier/tile, m97-style loop.
//   3) k_quant: per-token std -> thr -> clamped absmax -> fake-quant, in place

typedef __attribute__((ext_vector_type(8))) short bf16x8;
typedef __attribute__((ext_vector_type(4))) float f32x4;
typedef __attribute__((ext_vector_type(8))) unsigned short u16x8;

#define QMAX_F 127.0f
#define THR_SIG 3.0f
#define EPS_F 1e-6f

__device__ __forceinline__ unsigned short f2bf(float f) {
    unsigned int u = __builtin_bit_cast(unsigned int, f);
    unsigned int r = u + 0x7fffu + ((u >> 16) & 1u);
    return (unsigned short)(r >> 16);
}

__device__ __forceinline__ void gl_lds16(const unsigned short* g, unsigned short* l) {
    __builtin_amdgcn_global_load_lds((const __attribute__((address_space(1))) void*)g,
                                     (__attribute__((address_space(3))) void*)l, 16, 0, 0);
}

__global__ __launch_bounds__(256) void k_convert(const float* __restrict__ in,
                                                 unsigned short* __restrict__ out,
                                                 long long n) {
    long long i = ((long long)blockIdx.x * 256 + threadIdx.x) * 8;
    if (i + 8 <= n) {
        f32x4 a = *(const f32x4*)(in + i);
        f32x4 b = *(const f32x4*)(in + i + 4);
        u16x8 o;
#pragma unroll
        for (int j = 0; j < 4; ++j) { o[j] = f2bf(a[j]); o[4 + j] = f2bf(b[j]); }
        *(u16x8*)(out + i) = o;
    }
}

// ---------------------------------------------------------------------------
// 256x256x32 GEMM, C = A·B^T + bias. A[M][K], B[N][K] bf16 K-major.
// 512 thr = 8 waves (2M x 4N); per wave 128x64 out = acc[8][4] (16x16x32).
// LDS 64 KiB: [buf2][A 256x32 | B 256x32] bf16 -> 2 blocks/CU co-resident
// (regs ~244/wave incl AGPR: 4 waves/SIMD x 244 < 2048 pool). Cross-block
// overlap hides the per-tile vmcnt(0) drain and barrier spread (m114/m97).
//
// Swizzle (BK=32 variant): 16B slot s at row r holds logical slot
// s ^ ((r>>1)&3). Fragment ds_read (rows fr=0..15, stride 64B) then hits each
// bank pair exactly twice -> 2-way alias (free, m136). Staging: linear LDS
// dest (gl_lds), per-lane PRE-swizzled global source (both-sides, rule #21).
//
// Per K-tile t (1 barrier):
//   STAGE(t+1): 4 calls -> buf[(t+1)&1]   (read during t-1; boundary barrier
//                                          of t-1 separates: legal)
//   read 12 frags from buf[t&1] (compiler per-operand lgkm waits)
//   32 MFMA (independent; setprio wrapped)
//   vmcnt(0)  (own 4 stage loads; issued ~full tile earlier -> near-retired)
//   s_barrier (publishes all waves' staging; tile t+1 resident)
// ---------------------------------------------------------------------------
#define STGA32(h, tt)                                                     \
    gl_lds16(aSrc + (size_t)(h) * 128 * K + (size_t)(tt) * 32,            \
             &lds[((tt) & 1) * 16384 + (h) * 4096 + dstT])
#define STGB32(h, tt)                                                     \
    gl_lds16(bSrc + (size_t)(h) * 128 * K + (size_t)(tt) * 32,            \
             &lds[((tt) & 1) * 16384 + 8192 + (h) * 4096 + dstT])

__global__ __launch_bounds__(512, 4) void k_gemm32(const unsigned short* __restrict__ A,
                                                   const unsigned short* __restrict__ B,
                                                   const float* __restrict__ bias,
                                                   float* __restrict__ C,
                                                   int M, int N, int K) {
    __shared__ unsigned short lds[32768];  // 64 KiB

    const int nbn = N >> 8;
    const int nwg = gridDim.x;
    int lin = blockIdx.x;
    int swz = lin;
    if ((nwg & 7) == 0) {  // bijective XCD swizzle
        int cpx = nwg >> 3;
        swz = (lin & 7) * cpx + (lin >> 3);
    }
    const int bm = swz / nbn, bn = swz % nbn;
    const int rowBase = bm << 8, colBase = bn << 8;

    const int tid = threadIdx.x;
    const int lane = tid & 63, w = tid >> 6;
    const int wr = w >> 2, wc = w & 3;

    // staging: thread tid covers row (tid>>2) of the 128-row group, phys slot
    // tid&3; logical slot = phys ^ ((row>>1)&3) = (tid&3) ^ ((tid>>3)&3).
    const int srow = tid >> 2;
    const int sslot = (tid & 3) ^ ((tid >> 3) & 3);
    const unsigned short* aSrc = A + (size_t)(rowBase + srow) * K + sslot * 8;
    const unsigned short* bSrc = B + (size_t)(colBase + srow) * K + sslot * 8;
    const int dstT = tid * 8;  // linear 16B per thread

    // ds_read offsets (shorts): row stride 32 elems; phys slot = ks^((fr>>1)&3)
    const int fr = lane & 15;
    const int ks = lane >> 4;
    const int aps = ks ^ ((fr >> 1) & 3);
    const int aOff = (wr * 128 + fr) * 32 + aps * 8;
    const int bOff = (wc * 64 + fr) * 32 + aps * 8;

    f32x4 acc[8][4];
#pragma unroll
    for (int i = 0; i < 8; ++i)
#pragma unroll
        for (int j = 0; j < 4; ++j) acc[i][j] = (f32x4){0.f, 0.f, 0.f, 0.f};

    const int nt = K >> 5;

    // prologue: tile0 (4 calls); drain; barrier.
    STGA32(0, 0); STGA32(1, 0); STGB32(0, 0); STGB32(1, 0);
    asm volatile("s_waitcnt vmcnt(0)" ::: "memory");
    __builtin_amdgcn_sched_barrier(0);
    __builtin_amdgcn_s_barrier();

    for (int t = 0; t < nt; ++t) {
        const unsigned short* Ab = lds + (t & 1) * 16384;
        const unsigned short* Bb = Ab + 8192;

        // stage next tile first (targets buf[(t+1)&1], idle since end of t-1)
        if (t + 1 < nt) { STGA32(0, t + 1); STGA32(1, t + 1); STGB32(0, t + 1); STGB32(1, t + 1); }

        bf16x8 af[8], bf[4];
#pragma unroll
        for (int mi = 0; mi < 8; ++mi)
            af[mi] = *(const bf16x8*)(Ab + aOff + mi * 512);
#pragma unroll
        for (int ni = 0; ni < 4; ++ni)
            bf[ni] = *(const bf16x8*)(Bb + bOff + ni * 512);

        __builtin_amdgcn_s_setprio(1);
#pragma unroll
        for (int mi = 0; mi < 8; ++mi)
#pragma unroll
            for (int ni = 0; ni < 4; ++ni)
                acc[mi][ni] = __builtin_amdgcn_mfma_f32_16x16x32_bf16(
                    af[mi], bf[ni], acc[mi][ni], 0, 0, 0);
        __builtin_amdgcn_s_setprio(0);
        __builtin_amdgcn_sched_barrier(0);
        asm volatile("s_waitcnt vmcnt(0)" ::: "memory");  // own staging retired
        __builtin_amdgcn_sched_barrier(0);
        __builtin_amdgcn_s_barrier();  // tile t+1 resident for all waves
    }

    // epilogue: C/D layout col = lane&15, row = (lane>>4)*4 + r  [m89]
    const int rowoff = (lane >> 4) * 4;
#pragma unroll
    for (int ni = 0; ni < 4; ++ni) {
        int gc = colBase + wc * 64 + ni * 16 + fr;
        float bv = bias[gc];
#pragma unroll
        for (int mi = 0; mi < 8; ++mi) {
            int gr = rowBase + wr * 128 + mi * 16 + rowoff;
#pragma unroll
            for (int r = 0; r < 4; ++r)
                C[(size_t)(gr + r) * N + gc] = acc[mi][ni][r] + bv;
        }
    }
}

// Fallback (no ws): f32 inputs, convert during staging (padded LDS, reg-staged).
__global__ __launch_bounds__(256) void k_gemm_f32(const float* __restrict__ Av,
                                                  const float* __restrict__ Bv,
                                                  const float* __restrict__ bias,
                                                  float* __restrict__ C,
                                                  int M, int N, int K) {
    __shared__ unsigned short sA[128 * 40];
    __shared__ unsigned short sB[128 * 40];

    const int nbn = N / 128;
    const int nwg = gridDim.x;
    int lin = blockIdx.x;
    int swz = lin;
    if ((nwg & 7) == 0) {
        int cpx = nwg >> 3;
        swz = (lin & 7) * cpx + (lin >> 3);
    }
    const int bm = swz / nbn, bn = swz % nbn;
    const int rowBase = bm * 128, colBase = bn * 128;

    const int tid = threadIdx.x;
    const int lane = tid & 63, wave = tid >> 6;
    const int wr = wave >> 1, wc = wave & 1;
    const int fr = lane & 15;
    const int kblk = (lane >> 4) * 8;

    f32x4 acc[4][4];
#pragma unroll
    for (int i = 0; i < 4; ++i)
#pragma unroll
        for (int j = 0; j < 4; ++j) acc[i][j] = (f32x4){0.f, 0.f, 0.f, 0.f};

    const int nk = K / 32;
    for (int kt = 0; kt < nk; ++kt) {
        const int kb = kt * 32;
        __syncthreads();
#pragma unroll
        for (int cc = 0; cc < 2; ++cc) {
            int c = tid + cc * 256;
            int row = c >> 2;
            int k8 = (c & 3) * 8;
            const float* gA = Av + (size_t)(rowBase + row) * K + kb + k8;
            const float* gB = Bv + (size_t)(colBase + row) * K + kb + k8;
            f32x4 a0 = *(const f32x4*)gA, a1 = *(const f32x4*)(gA + 4);
            f32x4 b0 = *(const f32x4*)gB, b1 = *(const f32x4*)(gB + 4);
            u16x8 va, vb;
#pragma unroll
            for (int j = 0; j < 4; ++j) {
                va[j] = f2bf(a0[j]); va[4 + j] = f2bf(a1[j]);
                vb[j] = f2bf(b0[j]); vb[4 + j] = f2bf(b1[j]);
            }
            *(u16x8*)&sA[row * 40 + k8] = va;
            *(u16x8*)&sB[row * 40 + k8] = vb;
        }
        __syncthreads();

        bf16x8 af[4], bfrag[4];
#pragma unroll
        for (int mi = 0; mi < 4; ++mi)
            af[mi] = *(const bf16x8*)&sA[(wr * 64 + mi * 16 + fr) * 40 + kblk];
#pragma unroll
        for (int ni = 0; ni < 4; ++ni)
            bfrag[ni] = *(const bf16x8*)&sB[(wc * 64 + ni * 16 + fr) * 40 + kblk];
#pragma unroll
        for (int mi = 0; mi < 4; ++mi)
#pragma unroll
            for (int ni = 0; ni < 4; ++ni)
                acc[mi][ni] = __builtin_amdgcn_mfma_f32_16x16x32_bf16(
                    af[mi], bfrag[ni], acc[mi][ni], 0, 0, 0);
    }

    const int rowoff = (lane >> 4) * 4;
#pragma unroll
    for (int ni = 0; ni < 4; ++ni) {
        int gc = colBase + wc * 64 + ni * 16 + fr;
        float bv = bias[gc];
#pragma unroll
        for (int mi = 0; mi < 4; ++mi) {
            int gr = rowBase + wr * 64 + mi * 16 + rowoff;
#pragma unroll
            for (int r = 0; r < 4; ++r)
                C[(size_t)(gr + r) * N + gc] = acc[mi][ni][r] + bv;
        }
    }
}

// Per-token outlier-aware fake-quant, in place. One block per row of D=2048.
__global__ __launch_bounds__(256) void k_quant(float* __restrict__ y, int D) {
    float* p = y + (size_t)blockIdx.x * D;
    const int tid = threadIdx.x;
    f32x4 v0 = *(const f32x4*)(p + tid * 8);
    f32x4 v1 = *(const f32x4*)(p + tid * 8 + 4);

    float s = 0.f, ss = 0.f;
#pragma unroll
    for (int j = 0; j < 4; ++j) {
        s += v0[j] + v1[j];
        ss += v0[j] * v0[j] + v1[j] * v1[j];
    }
#pragma unroll
    for (int off = 32; off > 0; off >>= 1) {
        s += __shfl_down(s, off, 64);
        ss += __shfl_down(ss, off, 64);
    }

    __shared__ float rs[4], rss[4], bc[2];
    const int wave = tid >> 6, lane = tid & 63;
    if (lane == 0) { rs[wave] = s; rss[wave] = ss; }
    __syncthreads();
    if (tid == 0) {
        float S = rs[0] + rs[1] + rs[2] + rs[3];
        float SS = rss[0] + rss[1] + rss[2] + rss[3];
        float mean = S / (float)D;
        float var = fmaxf(SS / (float)D - mean * mean, 0.f);
        bc[0] = THR_SIG * sqrtf(var);
    }
    __syncthreads();
    const float thr = bc[0];

    float m = 0.f;
#pragma unroll
    for (int j = 0; j < 4; ++j) {
        m = fmaxf(m, fminf(fabsf(v0[j]), thr));
        m = fmaxf(m, fminf(fabsf(v1[j]), thr));
    }
#pragma unroll
    for (int off = 32; off > 0; off >>= 1) m = fmaxf(m, __shfl_down(m, off, 64));
    if (lane == 0) rs[wave] = m;
    __syncthreads();
    if (tid == 0) {
        float mm = fmaxf(fmaxf(rs[0], rs[1]), fmaxf(rs[2], rs[3]));
        bc[1] = fmaxf(mm / QMAX_F, EPS_F);
    }
    __syncthreads();
    const float scale = bc[1];

#pragma unroll
    for (int j = 0; j < 4; ++j) {
        {
            float v = v0[j];
            float c = fminf(fmaxf(v, -thr), thr);
            float q = rintf(c / scale) * scale;
            v0[j] = (fabsf(v) > thr) ? v : q;
        }
        {
            float v = v1[j];
            float c = fminf(fmaxf(v, -thr), thr);
            float q = rintf(c / scale) * scale;
            v1[j] = (fabsf(v) > thr) ? v : q;
        }
    }
    *(f32x4*)(p + tid * 8) = v0;
    *(f32x4*)(p + tid * 8 + 4) = v1;
}

extern "C" void kernel_launch(void* const* d_in, const int* in_sizes, int n_in,
                              void* d_out, int out_size, void* d_ws, size_t ws_size,
                              hipStream_t stream) {
    const float* x = (const float*)d_in[0];
    const float* W = (const float*)d_in[1];
    const float* b = (const float*)d_in[2];
    float* out = (float*)d_out;

    const int Dout = in_sizes[2];
    const int Din = in_sizes[1] / Dout;
    const int M = in_sizes[0] / Din;

    const size_t nA = (size_t)M * Din;
    const size_t nB = (size_t)Dout * Din;
    const size_t need = (nA + nB) * sizeof(unsigned short);
    const bool fits8 = (M % 256 == 0) && (Dout % 256 == 0) && (Din % 64 == 0) && (Din >= 256);
    const bool pre = (ws_size >= need) && fits8;

    if (pre) {
        unsigned short* xb = (unsigned short*)d_ws;
        unsigned short* wb = xb + nA;
        int gA = (int)((nA + 8 * 256 - 1) / (8 * 256));
        int gB = (int)((nB + 8 * 256 - 1) / (8 * 256));
        k_convert<<<gA, 256, 0, stream>>>(x, xb, (long long)nA);
        k_convert<<<gB, 256, 0, stream>>>(W, wb, (long long)nB);
        int gridGemm = (M / 256) * (Dout / 256);
        k_gemm32<<<gridGemm, 512, 0, stream>>>(xb, wb, b, out, M, Dout, Din);
    } else {
        int gridGemm = (M / 128) * (Dout / 128);
        k_gemm_f32<<<gridGemm, 256, 0, stream>>>(x, W, b, out, M, Dout, Din);
    }
    k_quant<<<M, 256, 0, stream>>>(out, Dout);
}

// Round 11
// 203.765 us; speedup vs baseline: 7.2120x; 7.2120x over previous
//
#include <hip/hip_runtime.h>
#include <hip/hip_bf16.h>

// OutlierAwareLinear: y = x @ W^T + b, then per-token outlier-aware fake-quant.
// M=16384 (B*S), K=2048 (D_in), N=2048 (D_out), all fp32 in/out.
//
// Pipeline:
//   1) k_convert2: x,W f32 -> bf16 into d_ws (single dual-range launch)
//   2) k_gemm8: 256x256x64 bf16 MFMA GEMM, 8 waves, ONE barrier per phase
//      (r9 schedule -- best measured: ~970 TF, MfmaUtil 41-43%)
//   3) k_quant: per-token std -> thr -> clamped absmax -> fake-quant, in place
//
// REGISTER MODEL (r10 errata): per-SIMD budget = 512 wave-registers TOTAL
// (8 waves x 64 = 4 x 128 = 2 x 256 = 1 x 512). acc[8][4] (128 AGPR) + ~116
// VGPR ~= 244/wave -> max 2 waves/SIMD -> ONE 8-wave block/CU. Forcing more
// occupancy (launch_bounds min-waves >= 4) spills acc to scratch (r10: 7 GB
// scratch traffic, 10x slowdown). Big-tile GEMM on gfx950 is 1-block/CU by
// construction; cross-block overlap is not available as a latency-hiding tool.

typedef __attribute__((ext_vector_type(8))) short bf16x8;
typedef __attribute__((ext_vector_type(4))) float f32x4;
typedef __attribute__((ext_vector_type(8))) unsigned short u16x8;

#define QMAX_F 127.0f
#define THR_SIG 3.0f
#define EPS_F 1e-6f

__device__ __forceinline__ unsigned short f2bf(float f) {
    unsigned int u = __builtin_bit_cast(unsigned int, f);
    unsigned int r = u + 0x7fffu + ((u >> 16) & 1u);
    return (unsigned short)(r >> 16);
}

__device__ __forceinline__ void gl_lds16(const unsigned short* g, unsigned short* l) {
    __builtin_amdgcn_global_load_lds((const __attribute__((address_space(1))) void*)g,
                                     (__attribute__((address_space(3))) void*)l, 16, 0, 0);
}

// dual-range convert: blocks [0,gA) cover in0[0..nA), blocks [gA,..) cover in1.
__global__ __launch_bounds__(256) void k_convert2(const float* __restrict__ in0,
                                                  unsigned short* __restrict__ out0,
                                                  long long nA, int gA,
                                                  const float* __restrict__ in1,
                                                  unsigned short* __restrict__ out1,
                                                  long long nB) {
    const float* in;
    unsigned short* out;
    long long n, i;
    if (blockIdx.x < (unsigned)gA) {
        in = in0; out = out0; n = nA;
        i = ((long long)blockIdx.x * 256 + threadIdx.x) * 8;
    } else {
        in = in1; out = out1; n = nB;
        i = ((long long)(blockIdx.x - gA) * 256 + threadIdx.x) * 8;
    }
    if (i + 8 <= n) {
        f32x4 a = *(const f32x4*)(in + i);
        f32x4 b = *(const f32x4*)(in + i + 4);
        u16x8 o;
#pragma unroll
        for (int j = 0; j < 4; ++j) { o[j] = f2bf(a[j]); o[4 + j] = f2bf(b[j]); }
        *(u16x8*)(out + i) = o;
    }
}

// ---------------------------------------------------------------------------
// 256x256x64 GEMM, C = A·B^T + bias. A[M][K], B[N][K] bf16 K-major.
// 512 thr = 8 waves (2M x 4N); per wave 128x64 out = acc[8][4] (16x16x32).
// LDS 128 KiB: [buf2][A/B][half2][128][64] bf16. T2 swizzle (slot^(row&7)),
// staging = linear LDS dest + pre-swizzled per-lane global source.
//
// ONE-BARRIER-PER-PHASE schedule (r9, best measured). Per K-tile t:
//   p1: read A(mi0-3)+B(ni0-1); stage Ah0(t+1); MFMA (m0,n0); bar
//   p2: read B(ni2-3);          stage Ah1(t+1); MFMA (m0,n1); bar
//   p3: read A(mi4-7);          stage Bh0(t+2); MFMA (m1,n1); bar
//   p4:                         stage Bh1(t+2); MFMA (m1,n0); vmcnt(4); bar
// Hazard ledger (all write-after-read edges keep >=1 END-phase barrier):
//   Ah0(t+1)@p1 -> A-half0 of buf[t^1] last read p3(t-1): 2 barriers.
//   Ah1(t+1)@p2 -> A-half1 of buf[t^1] last read p3(t-1): 3 barriers.
//   Bh0(t+2)@p3 -> B-half0 of buf[t]   last read p2(t):   1 barrier (end-p2).
//   Bh1(t+2)@p4 -> B-half1 of buf[t]   last read p2(t):   2 barriers.
// Within-phase: stage targets disjoint from the phase's read regions; a wave's
// own reads retire before its MFMAs (compiler lgkm waits) hence before its
// barrier arrival. Boundary vmcnt(4) is per-wave (own loads) BEFORE the
// barrier; barrier then publishes all waves' staging -> tile t+1 resident.
// Prologue: tile0 full (8 calls) + Bh0,Bh1(tile1) (4); vmcnt(4).
// ---------------------------------------------------------------------------
#define STGA(h, i, tt)                                                              \
    gl_lds16(aSrc + (size_t)((h) * 128 + (i) * 64) * K + (tt) * 64,                 \
             &lds[((tt) & 1) * 32768 + (h) * 8192 + (i) * 4096 + dstW])
#define STGB(h, i, tt)                                                              \
    gl_lds16(bSrc + (size_t)((h) * 128 + (i) * 64) * K + (tt) * 64,                 \
             &lds[((tt) & 1) * 32768 + 16384 + (h) * 8192 + (i) * 4096 + dstW])

__global__ __launch_bounds__(512, 2) void k_gemm8(const unsigned short* __restrict__ A,
                                                  const unsigned short* __restrict__ B,
                                                  const float* __restrict__ bias,
                                                  float* __restrict__ C,
                                                  int M, int N, int K) {
    __shared__ unsigned short lds[65536];  // 128 KiB

    const int nbn = N >> 8;
    const int nwg = gridDim.x;
    int lin = blockIdx.x;
    int swz = lin;
    if ((nwg & 7) == 0) {  // bijective XCD swizzle
        int cpx = nwg >> 3;
        swz = (lin & 7) * cpx + (lin >> 3);
    }
    const int bm = swz / nbn, bn = swz % nbn;
    const int rowBase = bm << 8, colBase = bn << 8;

    const int tid = threadIdx.x;
    const int lane = tid & 63, w = tid >> 6;
    const int wr = w >> 2, wc = w & 3;

    // staging: lane l covers row (base + l>>3), phys slot l&7 -> logical slot
    // (l&7)^(l>>3); global source pre-swizzled accordingly.
    const int lrow = lane >> 3;
    const int lslot = (lane & 7) ^ lrow;
    const unsigned short* aSrc = A + (size_t)(rowBase + w * 8 + lrow) * K + lslot * 8;
    const unsigned short* bSrc = B + (size_t)(colBase + w * 8 + lrow) * K + lslot * 8;
    const int dstW = w * 512;  // (w*8 rows)*64 elems

    // ds_read offsets (elems): row = (16-blk) + fr, phys slot = logical ^ (fr&7)
    const int fr = lane & 15;
    const int ps0 = (((lane >> 4) ^ (lane & 7))) * 8;  // ks=0; ks=1 -> ^32
    const int aO0 = wr * 8192 + fr * 64 + ps0;
    const int aO1 = wr * 8192 + fr * 64 + (ps0 ^ 32);
    const int bO0 = (wc >> 1) * 8192 + ((wc & 1) * 64 + fr) * 64 + ps0;
    const int bO1 = (wc >> 1) * 8192 + ((wc & 1) * 64 + fr) * 64 + (ps0 ^ 32);

    f32x4 acc[8][4];
#pragma unroll
    for (int i = 0; i < 8; ++i)
#pragma unroll
        for (int j = 0; j < 4; ++j) acc[i][j] = (f32x4){0.f, 0.f, 0.f, 0.f};

    const int nt = K >> 6;

    // prologue: tile0 full (8 loads) + Bh0,Bh1(tile1) (4 loads); vmcnt(4).
    STGA(0, 0, 0); STGA(0, 1, 0); STGA(1, 0, 0); STGA(1, 1, 0);
    STGB(0, 0, 0); STGB(0, 1, 0); STGB(1, 0, 0); STGB(1, 1, 0);
    STGB(0, 0, 1); STGB(0, 1, 1); STGB(1, 0, 1); STGB(1, 1, 1);
    asm volatile("s_waitcnt vmcnt(4)" ::: "memory");  // tile0 resident
    __builtin_amdgcn_sched_barrier(0);
    __builtin_amdgcn_s_barrier();

    for (int t = 0; t < nt; ++t) {
        const unsigned short* Ab = lds + (t & 1) * 32768;
        const unsigned short* Bb = Ab + 16384;
        bf16x8 aQ[8], bLo[4], bHi[4];

        // ---- phase 1: read A mi0-3 + B ni0-1; stage Ah0(t+1); MFMA (m0,n0); bar
#pragma unroll
        for (int mi = 0; mi < 4; ++mi) {
            aQ[2 * mi] = *(const bf16x8*)(Ab + aO0 + mi * 1024);
            aQ[2 * mi + 1] = *(const bf16x8*)(Ab + aO1 + mi * 1024);
        }
#pragma unroll
        for (int ni = 0; ni < 2; ++ni) {
            bLo[2 * ni] = *(const bf16x8*)(Bb + bO0 + ni * 1024);
            bLo[2 * ni + 1] = *(const bf16x8*)(Bb + bO1 + ni * 1024);
        }
        if (t + 1 < nt) { STGA(0, 0, t + 1); STGA(0, 1, t + 1); }
        __builtin_amdgcn_s_setprio(1);
#pragma unroll
        for (int mi = 0; mi < 4; ++mi)
#pragma unroll
            for (int ni = 0; ni < 2; ++ni) {
                acc[mi][ni] = __builtin_amdgcn_mfma_f32_16x16x32_bf16(
                    aQ[2 * mi], bLo[2 * ni], acc[mi][ni], 0, 0, 0);
                acc[mi][ni] = __builtin_amdgcn_mfma_f32_16x16x32_bf16(
                    aQ[2 * mi + 1], bLo[2 * ni + 1], acc[mi][ni], 0, 0, 0);
            }
        __builtin_amdgcn_s_setprio(0);
        __builtin_amdgcn_sched_barrier(0);
        __builtin_amdgcn_s_barrier();

        // ---- phase 2: read B ni2-3; stage Ah1(t+1); MFMA (m0,n1); bar
#pragma unroll
        for (int ni = 0; ni < 2; ++ni) {
            bHi[2 * ni] = *(const bf16x8*)(Bb + bO0 + (ni + 2) * 1024);
            bHi[2 * ni + 1] = *(const bf16x8*)(Bb + bO1 + (ni + 2) * 1024);
        }
        if (t + 1 < nt) { STGA(1, 0, t + 1); STGA(1, 1, t + 1); }
        __builtin_amdgcn_s_setprio(1);
#pragma unroll
        for (int mi = 0; mi < 4; ++mi)
#pragma unroll
            for (int ni = 0; ni < 2; ++ni) {
                acc[mi][2 + ni] = __builtin_amdgcn_mfma_f32_16x16x32_bf16(
                    aQ[2 * mi], bHi[2 * ni], acc[mi][2 + ni], 0, 0, 0);
                acc[mi][2 + ni] = __builtin_amdgcn_mfma_f32_16x16x32_bf16(
                    aQ[2 * mi + 1], bHi[2 * ni + 1], acc[mi][2 + ni], 0, 0, 0);
            }
        __builtin_amdgcn_s_setprio(0);
        __builtin_amdgcn_sched_barrier(0);
        __builtin_amdgcn_s_barrier();

        // ---- phase 3: read A mi4-7; stage Bh0(t+2); MFMA (m1,n1); bar
        // (B-half0 of buf[t] last read p2; end-of-p2 barrier separates)
#pragma unroll
        for (int mi = 0; mi < 4; ++mi) {
            aQ[2 * mi] = *(const bf16x8*)(Ab + aO0 + (mi + 4) * 1024);
            aQ[2 * mi + 1] = *(const bf16x8*)(Ab + aO1 + (mi + 4) * 1024);
        }
        if (t + 2 < nt) { STGB(0, 0, t + 2); STGB(0, 1, t + 2); }
        __builtin_amdgcn_s_setprio(1);
#pragma unroll
        for (int mi = 0; mi < 4; ++mi)
#pragma unroll
            for (int ni = 0; ni < 2; ++ni) {
                acc[4 + mi][2 + ni] = __builtin_amdgcn_mfma_f32_16x16x32_bf16(
                    aQ[2 * mi], bHi[2 * ni], acc[4 + mi][2 + ni], 0, 0, 0);
                acc[4 + mi][2 + ni] = __builtin_amdgcn_mfma_f32_16x16x32_bf16(
                    aQ[2 * mi + 1], bHi[2 * ni + 1], acc[4 + mi][2 + ni], 0, 0, 0);
            }
        __builtin_amdgcn_s_setprio(0);
        __builtin_amdgcn_sched_barrier(0);
        __builtin_amdgcn_s_barrier();

        // ---- phase 4: stage Bh1(t+2); MFMA (m1,n0); vmcnt(4); bar
        if (t + 2 < nt) { STGB(1, 0, t + 2); STGB(1, 1, t + 2); }
        __builtin_amdgcn_s_setprio(1);
#pragma unroll
        for (int mi = 0; mi < 4; ++mi)
#pragma unroll
            for (int ni = 0; ni < 2; ++ni) {
                acc[4 + mi][ni] = __builtin_amdgcn_mfma_f32_16x16x32_bf16(
                    aQ[2 * mi], bLo[2 * ni], acc[4 + mi][ni], 0, 0, 0);
                acc[4 + mi][ni] = __builtin_amdgcn_mfma_f32_16x16x32_bf16(
                    aQ[2 * mi + 1], bLo[2 * ni + 1], acc[4 + mi][ni], 0, 0, 0);
            }
        __builtin_amdgcn_s_setprio(0);
        __builtin_amdgcn_sched_barrier(0);
        if (t < nt - 2) {
            asm volatile("s_waitcnt vmcnt(4)" ::: "memory");  // tile t+1 resident
        } else {
            asm volatile("s_waitcnt vmcnt(0)" ::: "memory");
        }
        __builtin_amdgcn_sched_barrier(0);
        __builtin_amdgcn_s_barrier();
    }

    // epilogue: C/D layout col = lane&15, row = (lane>>4)*4 + r  [m89]
    const int rowoff = (lane >> 4) * 4;
#pragma unroll
    for (int ni = 0; ni < 4; ++ni) {
        int gc = colBase + wc * 64 + ni * 16 + fr;
        float bv = bias[gc];
#pragma unroll
        for (int mi = 0; mi < 8; ++mi) {
            int gr = rowBase + wr * 128 + mi * 16 + rowoff;
#pragma unroll
            for (int r = 0; r < 4; ++r)
                C[(size_t)(gr + r) * N + gc] = acc[mi][ni][r] + bv;
        }
    }
}

// Fallback (no ws): f32 inputs, convert during staging (padded LDS, reg-staged).
__global__ __launch_bounds__(256) void k_gemm_f32(const float* __restrict__ Av,
                                                  const float* __restrict__ Bv,
                                                  const float* __restrict__ bias,
                                                  float* __restrict__ C,
                                                  int M, int N, int K) {
    __shared__ unsigned short sA[128 * 40];
    __shared__ unsigned short sB[128 * 40];

    const int nbn = N / 128;
    const int nwg = gridDim.x;
    int lin = blockIdx.x;
    int swz = lin;
    if ((nwg & 7) == 0) {
        int cpx = nwg >> 3;
        swz = (lin & 7) * cpx + (lin >> 3);
    }
    const int bm = swz / nbn, bn = swz % nbn;
    const int rowBase = bm * 128, colBase = bn * 128;

    const int tid = threadIdx.x;
    const int lane = tid & 63, wave = tid >> 6;
    const int wr = wave >> 1, wc = wave & 1;
    const int fr = lane & 15;
    const int kblk = (lane >> 4) * 8;

    f32x4 acc[4][4];
#pragma unroll
    for (int i = 0; i < 4; ++i)
#pragma unroll
        for (int j = 0; j < 4; ++j) acc[i][j] = (f32x4){0.f, 0.f, 0.f, 0.f};

    const int nk = K / 32;
    for (int kt = 0; kt < nk; ++kt) {
        const int kb = kt * 32;
        __syncthreads();
#pragma unroll
        for (int cc = 0; cc < 2; ++cc) {
            int c = tid + cc * 256;
            int row = c >> 2;
            int k8 = (c & 3) * 8;
            const float* gA = Av + (size_t)(rowBase + row) * K + kb + k8;
            const float* gB = Bv + (size_t)(colBase + row) * K + kb + k8;
            f32x4 a0 = *(const f32x4*)gA, a1 = *(const f32x4*)(gA + 4);
            f32x4 b0 = *(const f32x4*)gB, b1 = *(const f32x4*)(gB + 4);
            u16x8 va, vb;
#pragma unroll
            for (int j = 0; j < 4; ++j) {
                va[j] = f2bf(a0[j]); va[4 + j] = f2bf(a1[j]);
                vb[j] = f2bf(b0[j]); vb[4 + j] = f2bf(b1[j]);
            }
            *(u16x8*)&sA[row * 40 + k8] = va;
            *(u16x8*)&sB[row * 40 + k8] = vb;
        }
        __syncthreads();

        bf16x8 af[4], bfrag[4];
#pragma unroll
        for (int mi = 0; mi < 4; ++mi)
            af[mi] = *(const bf16x8*)&sA[(wr * 64 + mi * 16 + fr) * 40 + kblk];
#pragma unroll
        for (int ni = 0; ni < 4; ++ni)
            bfrag[ni] = *(const bf16x8*)&sB[(wc * 64 + ni * 16 + fr) * 40 + kblk];
#pragma unroll
        for (int mi = 0; mi < 4; ++mi)
#pragma unroll
            for (int ni = 0; ni < 4; ++ni)
                acc[mi][ni] = __builtin_amdgcn_mfma_f32_16x16x32_bf16(
                    af[mi], bfrag[ni], acc[mi][ni], 0, 0, 0);
    }

    const int rowoff = (lane >> 4) * 4;
#pragma unroll
    for (int ni = 0; ni < 4; ++ni) {
        int gc = colBase + wc * 64 + ni * 16 + fr;
        float bv = bias[gc];
#pragma unroll
        for (int mi = 0; mi < 4; ++mi) {
            int gr = rowBase + wr * 64 + mi * 16 + rowoff;
#pragma unroll
            for (int r = 0; r < 4; ++r)
                C[(size_t)(gr + r) * N + gc] = acc[mi][ni][r] + bv;
        }
    }
}

// Per-token outlier-aware fake-quant, in place. One block per row of D=2048.
__global__ __launch_bounds__(256) void k_quant(float* __restrict__ y, int D) {
    float* p = y + (size_t)blockIdx.x * D;
    const int tid = threadIdx.x;
    f32x4 v0 = *(const f32x4*)(p + tid * 8);
    f32x4 v1 = *(const f32x4*)(p + tid * 8 + 4);

    float s = 0.f, ss = 0.f;
#pragma unroll
    for (int j = 0; j < 4; ++j) {
        s += v0[j] + v1[j];
        ss += v0[j] * v0[j] + v1[j] * v1[j];
    }
#pragma unroll
    for (int off = 32; off > 0; off >>= 1) {
        s += __shfl_down(s, off, 64);
        ss += __shfl_down(ss, off, 64);
    }

    __shared__ float rs[4], rss[4], bc[2];
    const int wave = tid >> 6, lane = tid & 63;
    if (lane == 0) { rs[wave] = s; rss[wave] = ss; }
    __syncthreads();
    if (tid == 0) {
        float S = rs[0] + rs[1] + rs[2] + rs[3];
        float SS = rss[0] + rss[1] + rss[2] + rss[3];
        float mean = S / (float)D;
        float var = fmaxf(SS / (float)D - mean * mean, 0.f);
        bc[0] = THR_SIG * sqrtf(var);
    }
    __syncthreads();
    const float thr = bc[0];

    float m = 0.f;
#pragma unroll
    for (int j = 0; j < 4; ++j) {
        m = fmaxf(m, fminf(fabsf(v0[j]), thr));
        m = fmaxf(m, fminf(fabsf(v1[j]), thr));
    }
#pragma unroll
    for (int off = 32; off > 0; off >>= 1) m = fmaxf(m, __shfl_down(m, off, 64));
    if (lane == 0) rs[wave] = m;
    __syncthreads();
    if (tid == 0) {
        float mm = fmaxf(fmaxf(rs[0], rs[1]), fmaxf(rs[2], rs[3]));
        bc[1] = fmaxf(mm / QMAX_F, EPS_F);
    }
    __syncthreads();
    const float scale = bc[1];

#pragma unroll
    for (int j = 0; j < 4; ++j) {
        {
            float v = v0[j];
            float c = fminf(fmaxf(v, -thr), thr);
            float q = rintf(c / scale) * scale;
            v0[j] = (fabsf(v) > thr) ? v : q;
        }
        {
            float v = v1[j];
            float c = fminf(fmaxf(v, -thr), thr);
            float q = rintf(c / scale) * scale;
            v1[j] = (fabsf(v) > thr) ? v : q;
        }
    }
    *(f32x4*)(p + tid * 8) = v0;
    *(f32x4*)(p + tid * 8 + 4) = v1;
}

extern "C" void kernel_launch(void* const* d_in, const int* in_sizes, int n_in,
                              void* d_out, int out_size, void* d_ws, size_t ws_size,
                              hipStream_t stream) {
    const float* x = (const float*)d_in[0];
    const float* W = (const float*)d_in[1];
    const float* b = (const float*)d_in[2];
    float* out = (float*)d_out;

    const int Dout = in_sizes[2];
    const int Din = in_sizes[1] / Dout;
    const int M = in_sizes[0] / Din;

    const size_t nA = (size_t)M * Din;
    const size_t nB = (size_t)Dout * Din;
    const size_t need = (nA + nB) * sizeof(unsigned short);
    const bool fits8 = (M % 256 == 0) && (Dout % 256 == 0) && (Din % 64 == 0) && (Din >= 256);
    const bool pre = (ws_size >= need) && fits8;

    if (pre) {
        unsigned short* xb = (unsigned short*)d_ws;
        unsigned short* wb = xb + nA;
        int gA = (int)((nA + 8 * 256 - 1) / (8 * 256));
        int gB = (int)((nB + 8 * 256 - 1) / (8 * 256));
        k_convert2<<<gA + gB, 256, 0, stream>>>(x, xb, (long long)nA, gA, W, wb, (long long)nB);
        int gridGemm = (M / 256) * (Dout / 256);
        k_gemm8<<<gridGemm, 512, 0, stream>>>(xb, wb, b, out, M, Dout, Din);
    } else {
        int gridGemm = (M / 128) * (Dout / 128);
        k_gemm_f32<<<gridGemm, 256, 0, stream>>>(x, W, b, out, M, Dout, Din);
    }
    k_quant<<<M, 256, 0, stream>>>(out, Dout);
}

// Round 12
// 194.100 us; speedup vs baseline: 7.5711x; 1.0498x over previous
//
#include <hip/hip_runtime.h>
#include <hip/hip_bf16.h>

// OutlierAwareLinear: y = x @ W^T + b, then per-token outlier-aware fake-quant.
// M=16384 (B*S), K=2048 (D_in), N=2048 (D_out), all fp32 in/out.
//
// Pipeline (fused path, ws permitting):
//   1) k_convert2: x,W f32 -> bf16 into d_ws (single dual-range launch)
//   2) k_gemm8<true>: r9-schedule GEMM; epilogue writes C' = bf16 4-row-tile
//      layout (C'[gr4][gc] = bf16x4 of rows 4*gr4..+3) into d_ws — one 8B
//      contiguous store per lane (vs 4 scalar f32), 67 MB instead of 134.
//   3) k_quant4: one block per 4 rows; reads C' coalesced (rows = f32x4
//      components, reductions component-wise), writes f32 out coalesced.
// Fallback (ws small): r11 path (f32 C + k_quant).
//
// REGISTER MODEL (r10 errata): per-SIMD budget = 512 wave-registers TOTAL.
// acc[8][4] (128 AGPR) + ~116 VGPR => 2 waves/SIMD max => ONE 8-wave block/CU.
// Forcing 4 waves/SIMD spills acc (r10: 7 GB scratch, 10x slowdown).
//
// ACCURACY (bf16 C'): adds <=0.0156 rounding on |y|<8; worst-case absmax
// ~0.031(GEMM bf16) + 0.024(one quant-step flip) + 0.016 ~= 0.07 < 0.117 thr.

typedef __attribute__((ext_vector_type(8))) short bf16x8;
typedef __attribute__((ext_vector_type(4))) float f32x4;
typedef __attribute__((ext_vector_type(8))) unsigned short u16x8;
typedef __attribute__((ext_vector_type(4))) unsigned short u16x4;

#define QMAX_F 127.0f
#define THR_SIG 3.0f
#define EPS_F 1e-6f

__device__ __forceinline__ unsigned short f2bf(float f) {
    unsigned int u = __builtin_bit_cast(unsigned int, f);
    unsigned int r = u + 0x7fffu + ((u >> 16) & 1u);
    return (unsigned short)(r >> 16);
}

__device__ __forceinline__ float bf2f(unsigned short h) {
    return __builtin_bit_cast(float, (unsigned int)h << 16);
}

__device__ __forceinline__ void gl_lds16(const unsigned short* g, unsigned short* l) {
    __builtin_amdgcn_global_load_lds((const __attribute__((address_space(1))) void*)g,
                                     (__attribute__((address_space(3))) void*)l, 16, 0, 0);
}

// dual-range convert: blocks [0,gA) cover in0[0..nA), blocks [gA,..) cover in1.
__global__ __launch_bounds__(256) void k_convert2(const float* __restrict__ in0,
                                                  unsigned short* __restrict__ out0,
                                                  long long nA, int gA,
                                                  const float* __restrict__ in1,
                                                  unsigned short* __restrict__ out1,
                                                  long long nB) {
    const float* in;
    unsigned short* out;
    long long n, i;
    if (blockIdx.x < (unsigned)gA) {
        in = in0; out = out0; n = nA;
        i = ((long long)blockIdx.x * 256 + threadIdx.x) * 8;
    } else {
        in = in1; out = out1; n = nB;
        i = ((long long)(blockIdx.x - gA) * 256 + threadIdx.x) * 8;
    }
    if (i + 8 <= n) {
        f32x4 a = *(const f32x4*)(in + i);
        f32x4 b = *(const f32x4*)(in + i + 4);
        u16x8 o;
#pragma unroll
        for (int j = 0; j < 4; ++j) { o[j] = f2bf(a[j]); o[4 + j] = f2bf(b[j]); }
        *(u16x8*)(out + i) = o;
    }
}

// ---------------------------------------------------------------------------
// 256x256x64 GEMM, C = A·B^T + bias. r9 one-barrier-per-phase schedule
// (best measured: ~970 TF). See hazard ledger in r9/r11 notes.
// TILEOUT=true: write bf16 C' tile layout to C4; else f32 C rows.
// ---------------------------------------------------------------------------
#define STGA(h, i, tt)                                                              \
    gl_lds16(aSrc + (size_t)((h) * 128 + (i) * 64) * K + (tt) * 64,                 \
             &lds[((tt) & 1) * 32768 + (h) * 8192 + (i) * 4096 + dstW])
#define STGB(h, i, tt)                                                              \
    gl_lds16(bSrc + (size_t)((h) * 128 + (i) * 64) * K + (tt) * 64,                 \
             &lds[((tt) & 1) * 32768 + 16384 + (h) * 8192 + (i) * 4096 + dstW])

template <bool TILEOUT>
__global__ __launch_bounds__(512, 2) void k_gemm8(const unsigned short* __restrict__ A,
                                                  const unsigned short* __restrict__ B,
                                                  const float* __restrict__ bias,
                                                  float* __restrict__ C,
                                                  u16x4* __restrict__ C4,
                                                  int M, int N, int K) {
    __shared__ unsigned short lds[65536];  // 128 KiB

    const int nbn = N >> 8;
    const int nwg = gridDim.x;
    int lin = blockIdx.x;
    int swz = lin;
    if ((nwg & 7) == 0) {  // bijective XCD swizzle
        int cpx = nwg >> 3;
        swz = (lin & 7) * cpx + (lin >> 3);
    }
    const int bm = swz / nbn, bn = swz % nbn;
    const int rowBase = bm << 8, colBase = bn << 8;

    const int tid = threadIdx.x;
    const int lane = tid & 63, w = tid >> 6;
    const int wr = w >> 2, wc = w & 3;

    const int lrow = lane >> 3;
    const int lslot = (lane & 7) ^ lrow;
    const unsigned short* aSrc = A + (size_t)(rowBase + w * 8 + lrow) * K + lslot * 8;
    const unsigned short* bSrc = B + (size_t)(colBase + w * 8 + lrow) * K + lslot * 8;
    const int dstW = w * 512;

    const int fr = lane & 15;
    const int ps0 = (((lane >> 4) ^ (lane & 7))) * 8;
    const int aO0 = wr * 8192 + fr * 64 + ps0;
    const int aO1 = wr * 8192 + fr * 64 + (ps0 ^ 32);
    const int bO0 = (wc >> 1) * 8192 + ((wc & 1) * 64 + fr) * 64 + ps0;
    const int bO1 = (wc >> 1) * 8192 + ((wc & 1) * 64 + fr) * 64 + (ps0 ^ 32);

    f32x4 acc[8][4];
#pragma unroll
    for (int i = 0; i < 8; ++i)
#pragma unroll
        for (int j = 0; j < 4; ++j) acc[i][j] = (f32x4){0.f, 0.f, 0.f, 0.f};

    const int nt = K >> 6;

    STGA(0, 0, 0); STGA(0, 1, 0); STGA(1, 0, 0); STGA(1, 1, 0);
    STGB(0, 0, 0); STGB(0, 1, 0); STGB(1, 0, 0); STGB(1, 1, 0);
    STGB(0, 0, 1); STGB(0, 1, 1); STGB(1, 0, 1); STGB(1, 1, 1);
    asm volatile("s_waitcnt vmcnt(4)" ::: "memory");
    __builtin_amdgcn_sched_barrier(0);
    __builtin_amdgcn_s_barrier();

    for (int t = 0; t < nt; ++t) {
        const unsigned short* Ab = lds + (t & 1) * 32768;
        const unsigned short* Bb = Ab + 16384;
        bf16x8 aQ[8], bLo[4], bHi[4];

        // p1: read A mi0-3 + B ni0-1; stage Ah0(t+1); MFMA (m0,n0); bar
#pragma unroll
        for (int mi = 0; mi < 4; ++mi) {
            aQ[2 * mi] = *(const bf16x8*)(Ab + aO0 + mi * 1024);
            aQ[2 * mi + 1] = *(const bf16x8*)(Ab + aO1 + mi * 1024);
        }
#pragma unroll
        for (int ni = 0; ni < 2; ++ni) {
            bLo[2 * ni] = *(const bf16x8*)(Bb + bO0 + ni * 1024);
            bLo[2 * ni + 1] = *(const bf16x8*)(Bb + bO1 + ni * 1024);
        }
        if (t + 1 < nt) { STGA(0, 0, t + 1); STGA(0, 1, t + 1); }
        __builtin_amdgcn_s_setprio(1);
#pragma unroll
        for (int mi = 0; mi < 4; ++mi)
#pragma unroll
            for (int ni = 0; ni < 2; ++ni) {
                acc[mi][ni] = __builtin_amdgcn_mfma_f32_16x16x32_bf16(
                    aQ[2 * mi], bLo[2 * ni], acc[mi][ni], 0, 0, 0);
                acc[mi][ni] = __builtin_amdgcn_mfma_f32_16x16x32_bf16(
                    aQ[2 * mi + 1], bLo[2 * ni + 1], acc[mi][ni], 0, 0, 0);
            }
        __builtin_amdgcn_s_setprio(0);
        __builtin_amdgcn_sched_barrier(0);
        __builtin_amdgcn_s_barrier();

        // p2: read B ni2-3; stage Ah1(t+1); MFMA (m0,n1); bar
#pragma unroll
        for (int ni = 0; ni < 2; ++ni) {
            bHi[2 * ni] = *(const bf16x8*)(Bb + bO0 + (ni + 2) * 1024);
            bHi[2 * ni + 1] = *(const bf16x8*)(Bb + bO1 + (ni + 2) * 1024);
        }
        if (t + 1 < nt) { STGA(1, 0, t + 1); STGA(1, 1, t + 1); }
        __builtin_amdgcn_s_setprio(1);
#pragma unroll
        for (int mi = 0; mi < 4; ++mi)
#pragma unroll
            for (int ni = 0; ni < 2; ++ni) {
                acc[mi][2 + ni] = __builtin_amdgcn_mfma_f32_16x16x32_bf16(
                    aQ[2 * mi], bHi[2 * ni], acc[mi][2 + ni], 0, 0, 0);
                acc[mi][2 + ni] = __builtin_amdgcn_mfma_f32_16x16x32_bf16(
                    aQ[2 * mi + 1], bHi[2 * ni + 1], acc[mi][2 + ni], 0, 0, 0);
            }
        __builtin_amdgcn_s_setprio(0);
        __builtin_amdgcn_sched_barrier(0);
        __builtin_amdgcn_s_barrier();

        // p3: read A mi4-7; stage Bh0(t+2); MFMA (m1,n1); bar
#pragma unroll
        for (int mi = 0; mi < 4; ++mi) {
            aQ[2 * mi] = *(const bf16x8*)(Ab + aO0 + (mi + 4) * 1024);
            aQ[2 * mi + 1] = *(const bf16x8*)(Ab + aO1 + (mi + 4) * 1024);
        }
        if (t + 2 < nt) { STGB(0, 0, t + 2); STGB(0, 1, t + 2); }
        __builtin_amdgcn_s_setprio(1);
#pragma unroll
        for (int mi = 0; mi < 4; ++mi)
#pragma unroll
            for (int ni = 0; ni < 2; ++ni) {
                acc[4 + mi][2 + ni] = __builtin_amdgcn_mfma_f32_16x16x32_bf16(
                    aQ[2 * mi], bHi[2 * ni], acc[4 + mi][2 + ni], 0, 0, 0);
                acc[4 + mi][2 + ni] = __builtin_amdgcn_mfma_f32_16x16x32_bf16(
                    aQ[2 * mi + 1], bHi[2 * ni + 1], acc[4 + mi][2 + ni], 0, 0, 0);
            }
        __builtin_amdgcn_s_setprio(0);
        __builtin_amdgcn_sched_barrier(0);
        __builtin_amdgcn_s_barrier();

        // p4: stage Bh1(t+2); MFMA (m1,n0); vmcnt(4); bar
        if (t + 2 < nt) { STGB(1, 0, t + 2); STGB(1, 1, t + 2); }
        __builtin_amdgcn_s_setprio(1);
#pragma unroll
        for (int mi = 0; mi < 4; ++mi)
#pragma unroll
            for (int ni = 0; ni < 2; ++ni) {
                acc[4 + mi][ni] = __builtin_amdgcn_mfma_f32_16x16x32_bf16(
                    aQ[2 * mi], bLo[2 * ni], acc[4 + mi][ni], 0, 0, 0);
                acc[4 + mi][ni] = __builtin_amdgcn_mfma_f32_16x16x32_bf16(
                    aQ[2 * mi + 1], bLo[2 * ni + 1], acc[4 + mi][ni], 0, 0, 0);
            }
        __builtin_amdgcn_s_setprio(0);
        __builtin_amdgcn_sched_barrier(0);
        if (t < nt - 2) {
            asm volatile("s_waitcnt vmcnt(4)" ::: "memory");
        } else {
            asm volatile("s_waitcnt vmcnt(0)" ::: "memory");
        }
        __builtin_amdgcn_sched_barrier(0);
        __builtin_amdgcn_s_barrier();
    }

    // epilogue: C/D layout col = lane&15, row = (lane>>4)*4 + r  [m89]
    if (TILEOUT) {
        // C'[gr4][gc] = bf16x4 of rows 4*gr4..+3: one contiguous 8B store/lane.
        const int gr4base = (rowBase + wr * 128) >> 2;
#pragma unroll
        for (int ni = 0; ni < 4; ++ni) {
            int gc = colBase + wc * 64 + ni * 16 + fr;
            float bv = bias[gc];
#pragma unroll
            for (int mi = 0; mi < 8; ++mi) {
                int gr4 = gr4base + mi * 4 + (lane >> 4);
                u16x4 o;
#pragma unroll
                for (int r = 0; r < 4; ++r) o[r] = f2bf(acc[mi][ni][r] + bv);
                C4[(size_t)gr4 * N + gc] = o;
            }
        }
    } else {
        const int rowoff = (lane >> 4) * 4;
#pragma unroll
        for (int ni = 0; ni < 4; ++ni) {
            int gc = colBase + wc * 64 + ni * 16 + fr;
            float bv = bias[gc];
#pragma unroll
            for (int mi = 0; mi < 8; ++mi) {
                int gr = rowBase + wr * 128 + mi * 16 + rowoff;
#pragma unroll
                for (int r = 0; r < 4; ++r)
                    C[(size_t)(gr + r) * N + gc] = acc[mi][ni][r] + bv;
            }
        }
    }
}

// ---------------------------------------------------------------------------
// k_quant4: one block per 4-row group of C' (bf16 tile layout, D=2048).
// Thread t, chunk i reads C'[g][i*256+t] (8B, lanes contiguous = 512B/wave);
// f32x4 components = 4 rows -> reductions component-wise, values stay in regs.
// Writes f32 out rows g*4+j, cols i*256+t (coalesced).
// ---------------------------------------------------------------------------
__global__ __launch_bounds__(256) void k_quant4(const u16x4* __restrict__ Cp,
                                                float* __restrict__ out, int D) {
    constexpr int CH = 8;  // D/256 == 8 (gated at launch)
    const int g = blockIdx.x, t = threadIdx.x;
    const u16x4* row = Cp + (size_t)g * D;

    f32x4 y[CH];
    f32x4 s = (f32x4){0.f, 0.f, 0.f, 0.f}, ss = s;
#pragma unroll
    for (int i = 0; i < CH; ++i) {
        u16x4 v = row[i * 256 + t];
#pragma unroll
        for (int j = 0; j < 4; ++j) y[i][j] = bf2f(v[j]);
        s += y[i];
        ss += y[i] * y[i];
    }
#pragma unroll
    for (int off = 32; off > 0; off >>= 1)
#pragma unroll
        for (int j = 0; j < 4; ++j) {
            s[j] += __shfl_down(s[j], off, 64);
            ss[j] += __shfl_down(ss[j], off, 64);
        }

    __shared__ f32x4 rs[4], rss[4], bc[2];
    const int wave = t >> 6, lane = t & 63;
    if (lane == 0) { rs[wave] = s; rss[wave] = ss; }
    __syncthreads();
    if (t == 0) {
        f32x4 S = rs[0] + rs[1] + rs[2] + rs[3];
        f32x4 SS = rss[0] + rss[1] + rss[2] + rss[3];
        f32x4 thr;
#pragma unroll
        for (int j = 0; j < 4; ++j) {
            float mean = S[j] / (float)2048;
            float var = fmaxf(SS[j] / (float)2048 - mean * mean, 0.f);
            thr[j] = THR_SIG * sqrtf(var);
        }
        bc[0] = thr;
    }
    __syncthreads();
    const f32x4 thr = bc[0];

    f32x4 m = (f32x4){0.f, 0.f, 0.f, 0.f};
#pragma unroll
    for (int i = 0; i < CH; ++i)
#pragma unroll
        for (int j = 0; j < 4; ++j)
            m[j] = fmaxf(m[j], fminf(fabsf(y[i][j]), thr[j]));
#pragma unroll
    for (int off = 32; off > 0; off >>= 1)
#pragma unroll
        for (int j = 0; j < 4; ++j) m[j] = fmaxf(m[j], __shfl_down(m[j], off, 64));
    if (lane == 0) rs[wave] = m;
    __syncthreads();
    if (t == 0) {
        f32x4 sc;
#pragma unroll
        for (int j = 0; j < 4; ++j) {
            float mm = fmaxf(fmaxf(rs[0][j], rs[1][j]), fmaxf(rs[2][j], rs[3][j]));
            sc[j] = fmaxf(mm / QMAX_F, EPS_F);
        }
        bc[1] = sc;
    }
    __syncthreads();
    const f32x4 scale = bc[1];

#pragma unroll
    for (int i = 0; i < CH; ++i)
#pragma unroll
        for (int j = 0; j < 4; ++j) {
            float v = y[i][j];
            float c = fminf(fmaxf(v, -thr[j]), thr[j]);
            float q = rintf(c / scale[j]) * scale[j];
            float res = (fabsf(v) > thr[j]) ? v : q;
            out[(size_t)(g * 4 + j) * D + i * 256 + t] = res;
        }
}

// Fallback (no ws): f32 inputs, convert during staging (padded LDS, reg-staged).
__global__ __launch_bounds__(256) void k_gemm_f32(const float* __restrict__ Av,
                                                  const float* __restrict__ Bv,
                                                  const float* __restrict__ bias,
                                                  float* __restrict__ C,
                                                  int M, int N, int K) {
    __shared__ unsigned short sA[128 * 40];
    __shared__ unsigned short sB[128 * 40];

    const int nbn = N / 128;
    const int nwg = gridDim.x;
    int lin = blockIdx.x;
    int swz = lin;
    if ((nwg & 7) == 0) {
        int cpx = nwg >> 3;
        swz = (lin & 7) * cpx + (lin >> 3);
    }
    const int bm = swz / nbn, bn = swz % nbn;
    const int rowBase = bm * 128, colBase = bn * 128;

    const int tid = threadIdx.x;
    const int lane = tid & 63, wave = tid >> 6;
    const int wr = wave >> 1, wc = wave & 1;
    const int fr = lane & 15;
    const int kblk = (lane >> 4) * 8;

    f32x4 acc[4][4];
#pragma unroll
    for (int i = 0; i < 4; ++i)
#pragma unroll
        for (int j = 0; j < 4; ++j) acc[i][j] = (f32x4){0.f, 0.f, 0.f, 0.f};

    const int nk = K / 32;
    for (int kt = 0; kt < nk; ++kt) {
        const int kb = kt * 32;
        __syncthreads();
#pragma unroll
        for (int cc = 0; cc < 2; ++cc) {
            int c = tid + cc * 256;
            int row = c >> 2;
            int k8 = (c & 3) * 8;
            const float* gA = Av + (size_t)(rowBase + row) * K + kb + k8;
            const float* gB = Bv + (size_t)(colBase + row) * K + kb + k8;
            f32x4 a0 = *(const f32x4*)gA, a1 = *(const f32x4*)(gA + 4);
            f32x4 b0 = *(const f32x4*)gB, b1 = *(const f32x4*)(gB + 4);
            u16x8 va, vb;
#pragma unroll
            for (int j = 0; j < 4; ++j) {
                va[j] = f2bf(a0[j]); va[4 + j] = f2bf(a1[j]);
                vb[j] = f2bf(b0[j]); vb[4 + j] = f2bf(b1[j]);
            }
            *(u16x8*)&sA[row * 40 + k8] = va;
            *(u16x8*)&sB[row * 40 + k8] = vb;
        }
        __syncthreads();

        bf16x8 af[4], bfrag[4];
#pragma unroll
        for (int mi = 0; mi < 4; ++mi)
            af[mi] = *(const bf16x8*)&sA[(wr * 64 + mi * 16 + fr) * 40 + kblk];
#pragma unroll
        for (int ni = 0; ni < 4; ++ni)
            bfrag[ni] = *(const bf16x8*)&sB[(wc * 64 + ni * 16 + fr) * 40 + kblk];
#pragma unroll
        for (int mi = 0; mi < 4; ++mi)
#pragma unroll
            for (int ni = 0; ni < 4; ++ni)
                acc[mi][ni] = __builtin_amdgcn_mfma_f32_16x16x32_bf16(
                    af[mi], bfrag[ni], acc[mi][ni], 0, 0, 0);
    }

    const int rowoff = (lane >> 4) * 4;
#pragma unroll
    for (int ni = 0; ni < 4; ++ni) {
        int gc = colBase + wc * 64 + ni * 16 + fr;
        float bv = bias[gc];
#pragma unroll
        for (int mi = 0; mi < 4; ++mi) {
            int gr = rowBase + wr * 64 + mi * 16 + rowoff;
#pragma unroll
            for (int r = 0; r < 4; ++r)
                C[(size_t)(gr + r) * N + gc] = acc[mi][ni][r] + bv;
        }
    }
}

// Per-token fake-quant fallback (f32 C rows), one block per row.
__global__ __launch_bounds__(256) void k_quant(float* __restrict__ y, int D) {
    float* p = y + (size_t)blockIdx.x * D;
    const int tid = threadIdx.x;
    f32x4 v0 = *(const f32x4*)(p + tid * 8);
    f32x4 v1 = *(const f32x4*)(p + tid * 8 + 4);

    float s = 0.f, ss = 0.f;
#pragma unroll
    for (int j = 0; j < 4; ++j) {
        s += v0[j] + v1[j];
        ss += v0[j] * v0[j] + v1[j] * v1[j];
    }
#pragma unroll
    for (int off = 32; off > 0; off >>= 1) {
        s += __shfl_down(s, off, 64);
        ss += __shfl_down(ss, off, 64);
    }

    __shared__ float rs[4], rss[4], bc[2];
    const int wave = tid >> 6, lane = tid & 63;
    if (lane == 0) { rs[wave] = s; rss[wave] = ss; }
    __syncthreads();
    if (tid == 0) {
        float S = rs[0] + rs[1] + rs[2] + rs[3];
        float SS = rss[0] + rss[1] + rss[2] + rss[3];
        float mean = S / (float)D;
        float var = fmaxf(SS / (float)D - mean * mean, 0.f);
        bc[0] = THR_SIG * sqrtf(var);
    }
    __syncthreads();
    const float thr = bc[0];

    float m = 0.f;
#pragma unroll
    for (int j = 0; j < 4; ++j) {
        m = fmaxf(m, fminf(fabsf(v0[j]), thr));
        m = fmaxf(m, fminf(fabsf(v1[j]), thr));
    }
#pragma unroll
    for (int off = 32; off > 0; off >>= 1) m = fmaxf(m, __shfl_down(m, off, 64));
    if (lane == 0) rs[wave] = m;
    __syncthreads();
    if (tid == 0) {
        float mm = fmaxf(fmaxf(rs[0], rs[1]), fmaxf(rs[2], rs[3]));
        bc[1] = fmaxf(mm / QMAX_F, EPS_F);
    }
    __syncthreads();
    const float scale = bc[1];

#pragma unroll
    for (int j = 0; j < 4; ++j) {
        {
            float v = v0[j];
            float c = fminf(fmaxf(v, -thr), thr);
            float q = rintf(c / scale) * scale;
            v0[j] = (fabsf(v) > thr) ? v : q;
        }
        {
            float v = v1[j];
            float c = fminf(fmaxf(v, -thr), thr);
            float q = rintf(c / scale) * scale;
            v1[j] = (fabsf(v) > thr) ? v : q;
        }
    }
    *(f32x4*)(p + tid * 8) = v0;
    *(f32x4*)(p + tid * 8 + 4) = v1;
}

extern "C" void kernel_launch(void* const* d_in, const int* in_sizes, int n_in,
                              void* d_out, int out_size, void* d_ws, size_t ws_size,
                              hipStream_t stream) {
    const float* x = (const float*)d_in[0];
    const float* W = (const float*)d_in[1];
    const float* b = (const float*)d_in[2];
    float* out = (float*)d_out;

    const int Dout = in_sizes[2];
    const int Din = in_sizes[1] / Dout;
    const int M = in_sizes[0] / Din;

    const size_t nA = (size_t)M * Din;
    const size_t nB = (size_t)Dout * Din;
    const size_t need = (nA + nB) * sizeof(unsigned short);
    const size_t need2 = need + (size_t)M * Dout * sizeof(unsigned short);
    const bool fits8 = (M % 256 == 0) && (Dout % 256 == 0) && (Din % 64 == 0) && (Din >= 256);
    const bool pre = (ws_size >= need) && fits8;
    const bool pre2 = pre && (ws_size >= need2) && (Dout == 2048) && (M % 4 == 0);

    if (pre) {
        unsigned short* xb = (unsigned short*)d_ws;
        unsigned short* wb = xb + nA;
        int gA = (int)((nA + 8 * 256 - 1) / (8 * 256));
        int gB = (int)((nB + 8 * 256 - 1) / (8 * 256));
        k_convert2<<<gA + gB, 256, 0, stream>>>(x, xb, (long long)nA, gA, W, wb, (long long)nB);
        int gridGemm = (M / 256) * (Dout / 256);
        if (pre2) {
            u16x4* C4 = (u16x4*)(wb + nB);
            k_gemm8<true><<<gridGemm, 512, 0, stream>>>(xb, wb, b, nullptr, C4, M, Dout, Din);
            k_quant4<<<M / 4, 256, 0, stream>>>(C4, out, Dout);
        } else {
            k_gemm8<false><<<gridGemm, 512, 0, stream>>>(xb, wb, b, out, nullptr, M, Dout, Din);
            k_quant<<<M, 256, 0, stream>>>(out, Dout);
        }
    } else {
        int gridGemm = (M / 128) * (Dout / 128);
        k_gemm_f32<<<gridGemm, 256, 0, stream>>>(x, W, b, out, M, Dout, Din);
        k_quant<<<M, 256, 0, stream>>>(out, Dout);
    }
}